// Round 6
// baseline (170.091 us; speedup 1.0000x reference)
//
#include <hip/hip_runtime.h>
#include <hip/hip_bf16.h>

typedef short bf16x8 __attribute__((ext_vector_type(8)));
typedef short bf16x4 __attribute__((ext_vector_type(4)));
typedef float f32x4 __attribute__((ext_vector_type(4)));
typedef unsigned short u16;

#define MFMA32(a, b, c) __builtin_amdgcn_mfma_f32_16x16x32_bf16(a, b, c, 0, 0, 0)

#if defined(__has_builtin)
#if __has_builtin(__builtin_amdgcn_mfma_f32_16x16x16bf16_1k)
#define HAVE_MFMA16 1
#define MFMA16(a, b, c) __builtin_amdgcn_mfma_f32_16x16x16bf16_1k(a, b, c, 0, 0, 0)
#endif
#endif
#ifndef HAVE_MFMA16
static __device__ inline f32x4 mfma16_asm(bf16x4 a, bf16x4 b, f32x4 c) {
    f32x4 d;
    asm volatile("v_mfma_f32_16x16x16_bf16 %0, %1, %2, %3\n\ts_nop 7\n\ts_nop 7"
                 : "=v"(d) : "v"(a), "v"(b), "v"(c));
    return d;
}
#define MFMA16(a, b, c) mfma16_asm(a, b, c)
#endif

__device__ inline float fexp2(float x) {
#if defined(__has_builtin) && __has_builtin(__builtin_amdgcn_exp2f)
    return __builtin_amdgcn_exp2f(x);
#else
    return exp2f(x);
#endif
}

__device__ inline u16 f2bf(float f) {
    unsigned u = __float_as_uint(f);
    unsigned r = (u + 0x7fffu + ((u >> 16) & 1u)) >> 16;
    return (u16)r;
}

__device__ inline float bf2f(u16 v) {
    return __uint_as_float(((unsigned)v) << 16);
}

__device__ inline void gload_lds16(const void* g, void* l) {
    __builtin_amdgcn_global_load_lds(
        (const __attribute__((address_space(1))) void*)g,
        (__attribute__((address_space(3))) void*)l, 16, 0, 0);
}

#define BARRIER() __builtin_amdgcn_s_barrier()

// swizzled byte offset inside a [rows][128B] tile (XOR swizzle, bank-conflict-free b128)
__device__ inline int swz(int row, int colbyte) {
    return row * 128 + (colbyte ^ ((row & 7) << 4));
}

// stage an 8KB [64 rows][128B] tile, 512 threads, 1x16B per thread (pre-swizzled source)
__device__ inline void stage8k_512(const u16* __restrict__ g, int gstride,
                                   u16* lds, int tid) {
    int o = tid * 16;
    int row = o >> 7;
    int colb = (o & 127) ^ ((row & 7) << 4);
    gload_lds16(g + row * gstride + (colb >> 1), (char*)lds + o);
}

// stage a 16KB [128 rows][128B] tile, 256 threads, 4x16B per thread
__device__ inline void stage16k_256(const u16* __restrict__ g, int gstride,
                                    u16* lds, int tid) {
#pragma unroll
    for (int j = 0; j < 4; j++) {
        int o = (tid + j * 256) * 16;
        int row = o >> 7;
        int colb = (o & 127) ^ ((row & 7) << 4);
        gload_lds16(g + row * gstride + (colb >> 1), (char*)lds + o);
    }
}

// ---------------- K0: f32 -> bf16 converts ----------------
__global__ void k_convert(const float* __restrict__ src, u16* __restrict__ dst, int n) {
    int i = (blockIdx.x * blockDim.x + threadIdx.x) * 4;
    if (i < n) {
        float4 v = *reinterpret_cast<const float4*>(src + i);
        ushort4 o;
        o.x = f2bf(v.x); o.y = f2bf(v.y); o.z = f2bf(v.z); o.w = f2bf(v.w);
        *reinterpret_cast<ushort4*>(dst + i) = o;
    }
}

__global__ void k_convert3(const float* __restrict__ s0, const float* __restrict__ s1,
                           const float* __restrict__ s2, u16* __restrict__ dst) {
    const float* s = (blockIdx.y == 0) ? s0 : ((blockIdx.y == 1) ? s1 : s2);
    int i = (blockIdx.x * blockDim.x + threadIdx.x) * 4;
    float4 v = *reinterpret_cast<const float4*>(s + i);
    ushort4 o;
    o.x = f2bf(v.x); o.y = f2bf(v.y); o.z = f2bf(v.z); o.w = f2bf(v.w);
    *reinterpret_cast<ushort4*>(dst + blockIdx.y * 1048576 + i) = o;
}

// ---------------- K1: projection GEMM  Y = xb @ W^T + b ----------------
// m97 structure: BK=64, single-buffered 32KB LDS, XOR-swizzled, 2 barriers/K-step.
// widx 0: Q (scaled by 0.125*log2e) -> [hb][s][c]; 1: K -> [hb][s][c]; 2: V -> Vt [hb][c][s]
__global__ __launch_bounds__(256, 3) void k_proj(
    const u16* __restrict__ xb, const u16* __restrict__ wb,
    const float* __restrict__ bq, const float* __restrict__ bk, const float* __restrict__ bv,
    u16* __restrict__ outQ, u16* __restrict__ outK, u16* __restrict__ outVt)
{
    __shared__ __align__(16) u16 As[8192];  // [128 m][64 k] swizzled
    __shared__ __align__(16) u16 Bs[8192];  // [128 n][64 k] swizzled
    const int tid = threadIdx.x;
    const int lane = tid & 63;
    const int w = tid >> 6;
    // XCD-aware 2-D partition over the 32m x 24n panel grid (768 blocks)
    const int bid = blockIdx.x;
    const int xcd = bid & 7, idx = bid >> 3;           // idx 0..95
    const int mg = xcd & 3, ng = xcd >> 2;
    const int m0 = (mg * 8 + (idx & 7)) * 128;
    const int nfull = ng * 12 + (idx >> 3);            // 0..23
    const int widx = nfull >> 3;
    const int n0 = (nfull & 7) * 128;
    const u16* W = wb + widx * 1024 * 1024;
    const float* bias = (widx == 0) ? bq : ((widx == 1) ? bk : bv);

    const int wm = (w >> 1) * 64, wn = (w & 1) * 64;
    const int lm = lane & 15, lg = lane >> 4;

    f32x4 zero = {0.f, 0.f, 0.f, 0.f};
    f32x4 acc[4][4];
#pragma unroll
    for (int m = 0; m < 4; m++)
#pragma unroll
        for (int n = 0; n < 4; n++) acc[m][n] = zero;

    for (int it = 0; it < 16; ++it) {
        stage16k_256(xb + m0 * 1024 + it * 64, 1024, As, tid);
        stage16k_256(W + n0 * 1024 + it * 64, 1024, Bs, tid);
        __syncthreads();
        const char* Ab = (const char*)As;
        const char* Bb = (const char*)Bs;
#pragma unroll
        for (int kk = 0; kk < 2; kk++) {
            bf16x8 a[4], b[4];
#pragma unroll
            for (int m = 0; m < 4; m++)
                a[m] = *(const bf16x8*)(Ab + swz(wm + m * 16 + lm, kk * 64 + lg * 16));
#pragma unroll
            for (int n = 0; n < 4; n++)
                b[n] = *(const bf16x8*)(Bb + swz(wn + n * 16 + lm, kk * 64 + lg * 16));
#pragma unroll
            for (int m = 0; m < 4; m++)
#pragma unroll
                for (int n = 0; n < 4; n++)
                    acc[m][n] = MFMA32(a[m], b[n], acc[m][n]);
        }
        __syncthreads();
    }

#pragma unroll
    for (int n = 0; n < 4; n++) {
        int col = n0 + wn + n * 16 + lm;
        float bz = bias[col];
        int h = col >> 6, c = col & 63;
#pragma unroll
        for (int m = 0; m < 4; m++) {
#pragma unroll
            for (int r = 0; r < 4; r++) {
                int row = m0 + wm + m * 16 + lg * 4 + r;
                float v = acc[m][n][r] + bz;
                int bb = row >> 10, s = row & 1023;
                int hb = h * 4 + bb;
                if (widx == 0) {
                    outQ[(hb * 1024 + s) * 64 + c] = f2bf(v * 0.18033688011112042f);
                } else if (widx == 1) {
                    outK[(hb * 1024 + s) * 64 + c] = f2bf(v);
                } else {
                    outVt[(hb * 64 + c) * 1024 + s] = f2bf(v);
                }
            }
        }
    }
}

// ---------------- K2: softmax denom per f-row; then V' = V * (1/l) in place ----------------
// 512 blocks (8 f-segs x 64 hb, head-per-XCD), 512 threads; K-head streamed once/block.
__global__ __launch_bounds__(512, 4) void k_stats(
    const u16* __restrict__ Q, const u16* __restrict__ K, u16* __restrict__ Vt)
{
    __shared__ __align__(16) u16 sK[2][4096];
    __shared__ float linv_lds[128];
    const int bid = blockIdx.x;
    const int hb = (bid & 7) * 8 + (bid >> 6);        // all 8 f-segs of a head on one XCD
    const int fb = ((bid >> 3) & 7) * 128;
    const int tid = threadIdx.x, lane = tid & 63, w = tid >> 6;
    const int lm = lane & 15, lg = lane >> 4;
    const u16* Qh = Q + hb * 65536;
    const u16* Kh = K + hb * 65536;
    u16* Vh = Vt + hb * 65536;

    // Q frags for this wave's 16 f rows
    const u16* qp = &Qh[(fb + w * 16 + lm) * 64 + lg * 8];
    bf16x8 a0 = *(const bf16x8*)qp;
    bf16x8 a1 = *(const bf16x8*)(qp + 32);

    float lrun[4] = {0.f, 0.f, 0.f, 0.f};

    stage8k_512(Kh, 64, sK[0], tid);
    int cur = 0;
    for (int it = 0; it < 16; ++it) {
        if (it < 15) {
            stage8k_512(Kh + (it + 1) * 64 * 64, 64, sK[cur ^ 1], tid);
            asm volatile("s_waitcnt vmcnt(1)" ::: "memory");
        } else {
            asm volatile("s_waitcnt vmcnt(0)" ::: "memory");
        }
        BARRIER();
        const char* base = (const char*)sK[cur];
#pragma unroll
        for (int n = 0; n < 4; n++) {
            int r = n * 16 + lm;
            bf16x8 b0 = *(const bf16x8*)(base + swz(r, lg * 16));
            bf16x8 b1 = *(const bf16x8*)(base + swz(r, 64 + lg * 16));
            f32x4 z = {0.f, 0.f, 0.f, 0.f};
            z = MFMA32(a0, b0, z);
            z = MFMA32(a1, b1, z);
            lrun[0] += fexp2(z[0]);
            lrun[1] += fexp2(z[1]);
            lrun[2] += fexp2(z[2]);
            lrun[3] += fexp2(z[3]);
        }
        BARRIER();
        cur ^= 1;
    }
#pragma unroll
    for (int r = 0; r < 4; r++) {
        float s = lrun[r];
        s += __shfl_xor(s, 1);
        s += __shfl_xor(s, 2);
        s += __shfl_xor(s, 4);
        s += __shfl_xor(s, 8);
        if (lm == 0) linv_lds[w * 16 + lg * 4 + r] = 1.0f / s;
    }
    __syncthreads();
    // V' = V * linv over this block's 128-f slice (Vt layout [c][f])
    {
        int c = tid >> 3, f8 = tid & 7;
#pragma unroll
        for (int j = 0; j < 2; j++) {
            int fl = f8 * 16 + j * 8;
            u16* vp = &Vh[c * 1024 + fb + fl];
            union { bf16x8 v; u16 e[8]; } uu, oo;
            uu.v = *(const bf16x8*)vp;
#pragma unroll
            for (int i = 0; i < 8; i++)
                oo.e[i] = f2bf(bf2f(uu.e[i]) * linv_lds[fl + i]);
            *(bf16x8*)vp = oo.v;
        }
    }
}

// ---------------- K3: av[t,c] = sum_f 2^S'[f,t] * V'[f,c] -> av_sb [hb][t][c] bf16 ----------------
// 512 blocks (8 t-segs x 64 hb, head-per-XCD), 512 threads; Q/V heads streamed once/block.
__global__ __launch_bounds__(512, 4) void k_av(
    const u16* __restrict__ Q, const u16* __restrict__ K, const u16* __restrict__ Vt,
    u16* __restrict__ av_sb)
{
    __shared__ __align__(16) u16 sQ[2][4096];
    __shared__ __align__(16) u16 sV[2][4096];
    const int bid = blockIdx.x;
    const int hb = (bid & 7) * 8 + (bid >> 6);        // all 8 t-segs of a head on one XCD
    const int tb = ((bid >> 3) & 7) * 128;
    const int tid = threadIdx.x, lane = tid & 63, w = tid >> 6;
    const int lm = lane & 15, lg = lane >> 4;
    const u16* Qh = Q + hb * 65536;
    const u16* Kh = K + hb * 65536;
    const u16* Vh = Vt + hb * 65536;

    // K frags for this wave's 16 t rows
    const u16* kp = &Kh[(tb + w * 16 + lm) * 64 + lg * 8];
    bf16x8 bK0 = *(const bf16x8*)kp;
    bf16x8 bK1 = *(const bf16x8*)(kp + 32);

    f32x4 zero = {0.f, 0.f, 0.f, 0.f};
    f32x4 accv[4];  // [c-tile m], full f-sum for this wave's 16 t
#pragma unroll
    for (int m = 0; m < 4; m++) accv[m] = zero;

    stage8k_512(Qh, 64, sQ[0], tid);
    stage8k_512(Vh, 1024, sV[0], tid);

    int cur = 0;
    for (int it = 0; it < 16; ++it) {
        if (it < 15) {
            int fn = (it + 1) * 64;
            stage8k_512(Qh + fn * 64, 64, sQ[cur ^ 1], tid);
            stage8k_512(Vh + fn, 1024, sV[cur ^ 1], tid);
            asm volatile("s_waitcnt vmcnt(2)" ::: "memory");
        } else {
            asm volatile("s_waitcnt vmcnt(0)" ::: "memory");
        }
        BARRIER();
        const char* Qb = (const char*)sQ[cur];
        const char* Vb = (const char*)sV[cur];

        // V' B-frags for MFMA16: [m: c-tile][kc: f-chunk]
        bf16x4 bv[4][4];
#pragma unroll
        for (int m = 0; m < 4; m++)
#pragma unroll
            for (int kc = 0; kc < 4; kc++)
                bv[m][kc] = *(const bf16x4*)(Vb + swz(m * 16 + lm, kc * 32 + lg * 8));

        // P fragments: S via MFMA32 (lane: t=lm, f=lg*4+r) == A-frag of 16x16x16
        bf16x4 afrag[4];
#pragma unroll
        for (int mq = 0; mq < 4; mq++) {
            bf16x8 aq0 = *(const bf16x8*)(Qb + swz(mq * 16 + lm, lg * 16));
            bf16x8 aq1 = *(const bf16x8*)(Qb + swz(mq * 16 + lm, 64 + lg * 16));
            f32x4 z = {0.f, 0.f, 0.f, 0.f};
            z = MFMA32(aq0, bK0, z);
            z = MFMA32(aq1, bK1, z);
            union { __hip_bfloat162 h2[2]; bf16x4 v4; } u;
            u.h2[0] = __float22bfloat162_rn(make_float2(fexp2(z[0]), fexp2(z[1])));
            u.h2[1] = __float22bfloat162_rn(make_float2(fexp2(z[2]), fexp2(z[3])));
            afrag[mq] = u.v4;
        }
#pragma unroll
        for (int m = 0; m < 4; m++)
#pragma unroll
            for (int kc = 0; kc < 4; kc++)
                accv[m] = MFMA16(afrag[kc], bv[m][kc], accv[m]);
        BARRIER();
        cur ^= 1;
    }

    // coalesced bf16 store to av_sb [hb][t][c]
#pragma unroll
    for (int m = 0; m < 4; m++) {
#pragma unroll
        for (int r = 0; r < 4; r++) {
            int t = tb + w * 16 + lg * 4 + r;
            av_sb[hb * 65536 + t * 64 + m * 16 + lm] = f2bf(accv[m][r]);
        }
    }
}

// ---------------- K4: channel-major interleave  out[b][t][c*16+h] = av_sb[h*4+b][t][c] ----------------
__global__ __launch_bounds__(256) void k_interleave(
    const u16* __restrict__ av_sb, float* __restrict__ out)
{
    const int bid = blockIdx.x;                 // 512 blocks
    const int bb = bid >> 7, ts = (bid & 127) * 8;
    const int c = threadIdx.x & 63, tl = threadIdx.x >> 6;
#pragma unroll
    for (int p = 0; p < 2; p++) {
        int t = ts + p * 4 + tl;
        float4 w[4];
#pragma unroll
        for (int q = 0; q < 4; q++) {
#pragma unroll
            for (int j = 0; j < 4; j++) {
                int h = q * 4 + j;
                ((float*)&w[q])[j] = bf2f(av_sb[((h * 4 + bb) * 1024 + t) * 64 + c]);
            }
        }
        float4* dst = (float4*)&out[(bb * 1024 + t) * 1024 + c * 16];
        dst[0] = w[0]; dst[1] = w[1]; dst[2] = w[2]; dst[3] = w[3];
    }
}

extern "C" void kernel_launch(void* const* d_in, const int* in_sizes, int n_in,
                              void* d_out, int out_size, void* d_ws, size_t ws_size,
                              hipStream_t stream) {
    const float* x  = (const float*)d_in[0];
    const float* Wq = (const float*)d_in[1];
    const float* bq = (const float*)d_in[2];
    const float* Wk = (const float*)d_in[3];
    const float* bk = (const float*)d_in[4];
    const float* Wv = (const float*)d_in[5];
    const float* bv = (const float*)d_in[6];
    float* out = (float*)d_out;
    char* ws = (char*)d_ws;

    u16* xb = (u16*)ws;                          // 8 MB  [4096][1024]  (dead after k_proj)
    u16* wb = (u16*)(ws + (8u << 20));           // 6 MB  [3][1024][1024]
    u16* Qb = (u16*)(ws + (14u << 20));          // 8 MB  [64][1024][64]
    u16* Kb = (u16*)(ws + (22u << 20));          // 8 MB  [64][1024][64]
    u16* Vt = (u16*)(ws + (30u << 20));          // 8 MB  [64][64][1024]
    u16* av_sb = (u16*)ws;                       // 8 MB  [64][1024][64] (reuses xb region)

    k_convert<<<4096, 256, 0, stream>>>(x, xb, 4096 * 1024);
    k_convert3<<<dim3(1024, 3), 256, 0, stream>>>(Wq, Wk, Wv, wb);
    k_proj<<<768, 256, 0, stream>>>(xb, wb, bq, bk, bv, Qb, Kb, Vt);
    k_stats<<<512, 512, 0, stream>>>(Qb, Kb, Vt);
    k_av<<<512, 512, 0, stream>>>(Qb, Kb, Vt, av_sb);
    k_interleave<<<512, 256, 0, stream>>>(av_sb, out);
}

// Round 7
// 103.849 us; speedup vs baseline: 1.6379x; 1.6379x over previous
//
#include <hip/hip_runtime.h>
#include <hip/hip_bf16.h>

typedef short bf16x8 __attribute__((ext_vector_type(8)));
typedef short bf16x4 __attribute__((ext_vector_type(4)));
typedef float f32x4 __attribute__((ext_vector_type(4)));
typedef unsigned short u16;

#define MFMA32(a, b, c) __builtin_amdgcn_mfma_f32_16x16x32_bf16(a, b, c, 0, 0, 0)

#if defined(__has_builtin)
#if __has_builtin(__builtin_amdgcn_mfma_f32_16x16x16bf16_1k)
#define HAVE_MFMA16 1
#define MFMA16(a, b, c) __builtin_amdgcn_mfma_f32_16x16x16bf16_1k(a, b, c, 0, 0, 0)
#endif
#endif
#ifndef HAVE_MFMA16
static __device__ inline f32x4 mfma16_asm(bf16x4 a, bf16x4 b, f32x4 c) {
    f32x4 d;
    asm volatile("v_mfma_f32_16x16x16_bf16 %0, %1, %2, %3\n\ts_nop 7\n\ts_nop 7"
                 : "=v"(d) : "v"(a), "v"(b), "v"(c));
    return d;
}
#define MFMA16(a, b, c) mfma16_asm(a, b, c)
#endif

__device__ inline float fexp2(float x) {
#if defined(__has_builtin) && __has_builtin(__builtin_amdgcn_exp2f)
    return __builtin_amdgcn_exp2f(x);
#else
    return exp2f(x);
#endif
}

__device__ inline u16 f2bf(float f) {
    unsigned u = __float_as_uint(f);
    unsigned r = (u + 0x7fffu + ((u >> 16) & 1u)) >> 16;
    return (u16)r;
}

__device__ inline float bf2f(u16 v) {
    return __uint_as_float(((unsigned)v) << 16);
}

__device__ inline void gload_lds16(const void* g, void* l) {
    __builtin_amdgcn_global_load_lds(
        (const __attribute__((address_space(1))) void*)g,
        (__attribute__((address_space(3))) void*)l, 16, 0, 0);
}

#define BARRIER() __builtin_amdgcn_s_barrier()

// swizzled byte offset inside a [rows][128B] tile (XOR swizzle, bank-conflict-free b128)
__device__ inline int swz(int row, int colbyte) {
    return row * 128 + (colbyte ^ ((row & 7) << 4));
}

// stage an 8KB [64 rows][128B] tile, 512 threads, 1x16B per thread (pre-swizzled source)
__device__ inline void stage8k_512(const u16* __restrict__ g, int gstride,
                                   u16* lds, int tid) {
    int o = tid * 16;
    int row = o >> 7;
    int colb = (o & 127) ^ ((row & 7) << 4);
    gload_lds16(g + row * gstride + (colb >> 1), (char*)lds + o);
}

// stage a 16KB [128 rows][128B] tile, 256 threads, 4x16B per thread
__device__ inline void stage16k_256(const u16* __restrict__ g, int gstride,
                                    u16* lds, int tid) {
#pragma unroll
    for (int j = 0; j < 4; j++) {
        int o = (tid + j * 256) * 16;
        int row = o >> 7;
        int colb = (o & 127) ^ ((row & 7) << 4);
        gload_lds16(g + row * gstride + (colb >> 1), (char*)lds + o);
    }
}

// ---------------- K0: f32 -> bf16 converts ----------------
__global__ void k_convert(const float* __restrict__ src, u16* __restrict__ dst, int n) {
    int i = (blockIdx.x * blockDim.x + threadIdx.x) * 4;
    if (i < n) {
        float4 v = *reinterpret_cast<const float4*>(src + i);
        ushort4 o;
        o.x = f2bf(v.x); o.y = f2bf(v.y); o.z = f2bf(v.z); o.w = f2bf(v.w);
        *reinterpret_cast<ushort4*>(dst + i) = o;
    }
}

__global__ void k_convert3(const float* __restrict__ s0, const float* __restrict__ s1,
                           const float* __restrict__ s2, u16* __restrict__ dst) {
    const float* s = (blockIdx.y == 0) ? s0 : ((blockIdx.y == 1) ? s1 : s2);
    int i = (blockIdx.x * blockDim.x + threadIdx.x) * 4;
    float4 v = *reinterpret_cast<const float4*>(s + i);
    ushort4 o;
    o.x = f2bf(v.x); o.y = f2bf(v.y); o.z = f2bf(v.z); o.w = f2bf(v.w);
    *reinterpret_cast<ushort4*>(dst + blockIdx.y * 1048576 + i) = o;
}

// ---------------- K1: projection GEMM  Y = xb @ W^T + b ----------------
// m97 structure: BK=64, single-buffered 32KB LDS, XOR-swizzled, 2 barriers/K-step.
// widx 0: Q (scaled by 0.125*log2e) -> [hb][s][c]; 1: K -> [hb][s][c]; 2: V -> Vt [hb][c][s]
__global__ __launch_bounds__(256, 3) void k_proj(
    const u16* __restrict__ xb, const u16* __restrict__ wb,
    const float* __restrict__ bq, const float* __restrict__ bk, const float* __restrict__ bv,
    u16* __restrict__ outQ, u16* __restrict__ outK, u16* __restrict__ outVt)
{
    __shared__ __align__(16) u16 As[8192];  // [128 m][64 k] swizzled
    __shared__ __align__(16) u16 Bs[8192];  // [128 n][64 k] swizzled
    const int tid = threadIdx.x;
    const int lane = tid & 63;
    const int w = tid >> 6;
    // XCD-aware 2-D partition over the 32m x 24n panel grid (768 blocks)
    const int bid = blockIdx.x;
    const int xcd = bid & 7, idx = bid >> 3;           // idx 0..95
    const int mg = xcd & 3, ng = xcd >> 2;
    const int m0 = (mg * 8 + (idx & 7)) * 128;
    const int nfull = ng * 12 + (idx >> 3);            // 0..23
    const int widx = nfull >> 3;
    const int n0 = (nfull & 7) * 128;
    const u16* W = wb + widx * 1024 * 1024;
    const float* bias = (widx == 0) ? bq : ((widx == 1) ? bk : bv);

    const int wm = (w >> 1) * 64, wn = (w & 1) * 64;
    const int lm = lane & 15, lg = lane >> 4;

    f32x4 zero = {0.f, 0.f, 0.f, 0.f};
    f32x4 acc[4][4];
#pragma unroll
    for (int m = 0; m < 4; m++)
#pragma unroll
        for (int n = 0; n < 4; n++) acc[m][n] = zero;

    for (int it = 0; it < 16; ++it) {
        stage16k_256(xb + m0 * 1024 + it * 64, 1024, As, tid);
        stage16k_256(W + n0 * 1024 + it * 64, 1024, Bs, tid);
        __syncthreads();
        const char* Ab = (const char*)As;
        const char* Bb = (const char*)Bs;
#pragma unroll
        for (int kk = 0; kk < 2; kk++) {
            bf16x8 a[4], b[4];
#pragma unroll
            for (int m = 0; m < 4; m++)
                a[m] = *(const bf16x8*)(Ab + swz(wm + m * 16 + lm, kk * 64 + lg * 16));
#pragma unroll
            for (int n = 0; n < 4; n++)
                b[n] = *(const bf16x8*)(Bb + swz(wn + n * 16 + lm, kk * 64 + lg * 16));
#pragma unroll
            for (int m = 0; m < 4; m++)
#pragma unroll
                for (int n = 0; n < 4; n++)
                    acc[m][n] = MFMA32(a[m], b[n], acc[m][n]);
        }
        __syncthreads();
    }

#pragma unroll
    for (int n = 0; n < 4; n++) {
        int col = n0 + wn + n * 16 + lm;
        float bz = bias[col];
        int h = col >> 6, c = col & 63;
#pragma unroll
        for (int m = 0; m < 4; m++) {
#pragma unroll
            for (int r = 0; r < 4; r++) {
                int row = m0 + wm + m * 16 + lg * 4 + r;
                float v = acc[m][n][r] + bz;
                int bb = row >> 10, s = row & 1023;
                int hb = h * 4 + bb;
                if (widx == 0) {
                    outQ[(hb * 1024 + s) * 64 + c] = f2bf(v * 0.18033688011112042f);
                } else if (widx == 1) {
                    outK[(hb * 1024 + s) * 64 + c] = f2bf(v);
                } else {
                    outVt[(hb * 64 + c) * 1024 + s] = f2bf(v);
                }
            }
        }
    }
}

// ---------------- K2: softmax denom (1/l) per f-row — PURE READ ----------------
// 256 blocks (4 f-segs x 64 hb, head-per-XCD grouping), 512 threads.
// Each wave owns 32 f rows (2 fragment groups); K-head streamed once per block.
__global__ __launch_bounds__(512, 2) void k_stats(
    const u16* __restrict__ Q, const u16* __restrict__ K, float* __restrict__ linv_out)
{
    __shared__ __align__(16) u16 sK[2][4096];
    const int bid = blockIdx.x;
    const int hb = (bid & 7) * 8 + ((bid >> 3) & 7);  // 8 heads per XCD
    const int fb = (bid >> 6) * 256;
    const int tid = threadIdx.x, lane = tid & 63, w = tid >> 6;
    const int lm = lane & 15, lg = lane >> 4;
    const u16* Qh = Q + hb * 65536;
    const u16* Kh = K + hb * 65536;

    // Q frags for this wave's 32 f rows (2 groups of 16)
    bf16x8 a[2][2];
#pragma unroll
    for (int fg = 0; fg < 2; fg++) {
        const u16* qp = &Qh[(fb + w * 32 + fg * 16 + lm) * 64 + lg * 8];
        a[fg][0] = *(const bf16x8*)qp;
        a[fg][1] = *(const bf16x8*)(qp + 32);
    }

    float lrun[2][4] = {{0.f, 0.f, 0.f, 0.f}, {0.f, 0.f, 0.f, 0.f}};

    stage8k_512(Kh, 64, sK[0], tid);
    int cur = 0;
    for (int it = 0; it < 16; ++it) {
        if (it < 15) {
            stage8k_512(Kh + (it + 1) * 64 * 64, 64, sK[cur ^ 1], tid);
            asm volatile("s_waitcnt vmcnt(1)" ::: "memory");
        } else {
            asm volatile("s_waitcnt vmcnt(0)" ::: "memory");
        }
        BARRIER();
        const char* base = (const char*)sK[cur];
#pragma unroll
        for (int n = 0; n < 4; n++) {
            int r = n * 16 + lm;
            bf16x8 b0 = *(const bf16x8*)(base + swz(r, lg * 16));
            bf16x8 b1 = *(const bf16x8*)(base + swz(r, 64 + lg * 16));
#pragma unroll
            for (int fg = 0; fg < 2; fg++) {
                f32x4 z = {0.f, 0.f, 0.f, 0.f};
                z = MFMA32(a[fg][0], b0, z);
                z = MFMA32(a[fg][1], b1, z);
                lrun[fg][0] += fexp2(z[0]);
                lrun[fg][1] += fexp2(z[1]);
                lrun[fg][2] += fexp2(z[2]);
                lrun[fg][3] += fexp2(z[3]);
            }
        }
        BARRIER();
        cur ^= 1;
    }
#pragma unroll
    for (int fg = 0; fg < 2; fg++) {
#pragma unroll
        for (int r = 0; r < 4; r++) {
            float s = lrun[fg][r];
            s += __shfl_xor(s, 1);
            s += __shfl_xor(s, 2);
            s += __shfl_xor(s, 4);
            s += __shfl_xor(s, 8);
            if (lm == 0)
                linv_out[hb * 1024 + fb + w * 32 + fg * 16 + lg * 4 + r] = 1.0f / s;
        }
    }
}

// ---------------- K3: av[t,c] = sum_f (2^S'[f,t] * linv[f]) * V[f,c] -> av_sb bf16 ----------------
// 256 blocks (4 t-segs x 64 hb, head-per-XCD), 512 threads; wave owns 32 t (2 groups);
// Q/V heads streamed once per block; linv row (4KB) staged in LDS once.
__global__ __launch_bounds__(512, 2) void k_av(
    const u16* __restrict__ Q, const u16* __restrict__ K, const u16* __restrict__ Vt,
    const float* __restrict__ linv, u16* __restrict__ av_sb)
{
    __shared__ __align__(16) u16 sQ[2][4096];
    __shared__ __align__(16) u16 sV[2][4096];
    __shared__ __align__(16) float linv_lds[1024];
    const int bid = blockIdx.x;
    const int hb = (bid & 7) * 8 + ((bid >> 3) & 7);
    const int tb = (bid >> 6) * 256;
    const int tid = threadIdx.x, lane = tid & 63, w = tid >> 6;
    const int lm = lane & 15, lg = lane >> 4;
    const u16* Qh = Q + hb * 65536;
    const u16* Kh = K + hb * 65536;
    const u16* Vh = Vt + hb * 65536;
    const float* lh = linv + hb * 1024;

    // K frags for this wave's 32 t rows (2 groups of 16)
    bf16x8 bK[2][2];
#pragma unroll
    for (int tg = 0; tg < 2; tg++) {
        const u16* kp = &Kh[(tb + w * 32 + tg * 16 + lm) * 64 + lg * 8];
        bK[tg][0] = *(const bf16x8*)kp;
        bK[tg][1] = *(const bf16x8*)(kp + 32);
    }

    f32x4 zero = {0.f, 0.f, 0.f, 0.f};
    f32x4 accv[2][4];  // [tg][c-tile m]
#pragma unroll
    for (int tg = 0; tg < 2; tg++)
#pragma unroll
        for (int m = 0; m < 4; m++) accv[tg][m] = zero;

    // prologue: stage first tiles + linv row; one full drain
    stage8k_512(Qh, 64, sQ[0], tid);
    stage8k_512(Vh, 1024, sV[0], tid);
    *reinterpret_cast<float2*>(&linv_lds[tid * 2]) =
        *reinterpret_cast<const float2*>(&lh[tid * 2]);
    __syncthreads();   // drains stages + linv LDS writes

    int cur = 0;
    for (int it = 0; it < 16; ++it) {
        if (it < 15) {
            int fn = (it + 1) * 64;
            stage8k_512(Qh + fn * 64, 64, sQ[cur ^ 1], tid);
            stage8k_512(Vh + fn, 1024, sV[cur ^ 1], tid);
            asm volatile("s_waitcnt vmcnt(2)" ::: "memory");
        } else {
            asm volatile("s_waitcnt vmcnt(0)" ::: "memory");
        }
        if (it > 0) BARRIER();   // it==0 already synced by __syncthreads
        const char* Qb = (const char*)sQ[cur];
        const char* Vb = (const char*)sV[cur];
        const int fc = it * 64;

        // P fragments: S via MFMA32 (lane: t=lm, f=mq*16+lg*4+r) feeds MFMA16 A-frags
        bf16x4 afrag[2][4];
#pragma unroll
        for (int mq = 0; mq < 4; mq++) {
            bf16x8 aq0 = *(const bf16x8*)(Qb + swz(mq * 16 + lm, lg * 16));
            bf16x8 aq1 = *(const bf16x8*)(Qb + swz(mq * 16 + lm, 64 + lg * 16));
            float4 lv = *reinterpret_cast<const float4*>(&linv_lds[fc + mq * 16 + lg * 4]);
#pragma unroll
            for (int tg = 0; tg < 2; tg++) {
                f32x4 z = {0.f, 0.f, 0.f, 0.f};
                z = MFMA32(aq0, bK[tg][0], z);
                z = MFMA32(aq1, bK[tg][1], z);
                union { __hip_bfloat162 h2[2]; bf16x4 v4; } u;
                u.h2[0] = __float22bfloat162_rn(
                    make_float2(fexp2(z[0]) * lv.x, fexp2(z[1]) * lv.y));
                u.h2[1] = __float22bfloat162_rn(
                    make_float2(fexp2(z[2]) * lv.z, fexp2(z[3]) * lv.w));
                afrag[tg][mq] = u.v4;
            }
        }
        // V B-frags for MFMA16: [m: c-tile][kc: f-chunk]
#pragma unroll
        for (int m = 0; m < 4; m++) {
#pragma unroll
            for (int kc = 0; kc < 4; kc++) {
                bf16x4 bv = *(const bf16x4*)(Vb + swz(m * 16 + lm, kc * 32 + lg * 8));
#pragma unroll
                for (int tg = 0; tg < 2; tg++)
                    accv[tg][m] = MFMA16(afrag[tg][kc], bv, accv[tg][m]);
            }
        }
        BARRIER();
        cur ^= 1;
    }

    // coalesced bf16 store to av_sb [hb][t][c]
#pragma unroll
    for (int tg = 0; tg < 2; tg++) {
#pragma unroll
        for (int m = 0; m < 4; m++) {
#pragma unroll
            for (int r = 0; r < 4; r++) {
                int t = tb + w * 32 + tg * 16 + lg * 4 + r;
                av_sb[hb * 65536 + t * 64 + m * 16 + lm] = f2bf(accv[tg][m][r]);
            }
        }
    }
}

// ---------------- K4: channel-major interleave  out[b][t][c*16+h] = av_sb[h*4+b][t][c] ----------------
__global__ __launch_bounds__(256) void k_interleave(
    const u16* __restrict__ av_sb, float* __restrict__ out)
{
    const int bid = blockIdx.x;                 // 512 blocks
    const int bb = bid >> 7, ts = (bid & 127) * 8;
    const int c = threadIdx.x & 63, tl = threadIdx.x >> 6;
#pragma unroll
    for (int p = 0; p < 2; p++) {
        int t = ts + p * 4 + tl;
        float4 w[4];
#pragma unroll
        for (int q = 0; q < 4; q++) {
#pragma unroll
            for (int j = 0; j < 4; j++) {
                int h = q * 4 + j;
                ((float*)&w[q])[j] = bf2f(av_sb[((h * 4 + bb) * 1024 + t) * 64 + c]);
            }
        }
        float4* dst = (float4*)&out[(bb * 1024 + t) * 1024 + c * 16];
        dst[0] = w[0]; dst[1] = w[1]; dst[2] = w[2]; dst[3] = w[3];
    }
}

extern "C" void kernel_launch(void* const* d_in, const int* in_sizes, int n_in,
                              void* d_out, int out_size, void* d_ws, size_t ws_size,
                              hipStream_t stream) {
    const float* x  = (const float*)d_in[0];
    const float* Wq = (const float*)d_in[1];
    const float* bq = (const float*)d_in[2];
    const float* Wk = (const float*)d_in[3];
    const float* bk = (const float*)d_in[4];
    const float* Wv = (const float*)d_in[5];
    const float* bv = (const float*)d_in[6];
    float* out = (float*)d_out;
    char* ws = (char*)d_ws;

    u16* xb = (u16*)ws;                          // 8 MB  [4096][1024]  (dead after k_proj)
    u16* wb = (u16*)(ws + (8u << 20));           // 6 MB  [3][1024][1024]
    u16* Qb = (u16*)(ws + (14u << 20));          // 8 MB  [64][1024][64]
    u16* Kb = (u16*)(ws + (22u << 20));          // 8 MB  [64][1024][64]
    u16* Vt = (u16*)(ws + (30u << 20));          // 8 MB  [64][64][1024]
    float* linv = (float*)(ws + (38u << 20));    // 256 KB [64][1024]
    u16* av_sb = (u16*)ws;                       // 8 MB  [64][1024][64] (reuses xb region)

    k_convert<<<4096, 256, 0, stream>>>(x, xb, 4096 * 1024);
    k_convert3<<<dim3(1024, 3), 256, 0, stream>>>(Wq, Wk, Wv, wb);
    k_proj<<<768, 256, 0, stream>>>(xb, wb, bq, bk, bv, Qb, Kb, Vt);
    k_stats<<<256, 512, 0, stream>>>(Qb, Kb, linv);
    k_av<<<256, 512, 0, stream>>>(Qb, Kb, Vt, linv, av_sb);
    k_interleave<<<512, 256, 0, stream>>>(av_sb, out);
}